// Round 7
// baseline (113.418 us; speedup 1.0000x reference)
//
#include <hip/hip_runtime.h>

// TropConv2D: out[b,ho,wo,f] = max_k(patch_k + w[k,f]) - min_k(patch_k + w[k,f])
// x: (8,32,32,32) f32 NHWC, w: (288,64) f32, out: (8,30,30,64) f32
// k = (i*3 + j)*32 + c   (TF extract_patches ordering)
//
// v7: LANE TRANSPOSITION. v2/v5/v6 (lane=filter) all plateau at kernel
//   ~14-15 us because the patch broadcast needs ~2160 uniform reads/CU
//   (ds_read_b128 or K$), ~11 us of read-pipe serialization -- structural
//   to that layout. v7 puts PIXEL in lane, FILTER in loop:
//   - patch data = per-lane VGPRs via ~72 global_load_dwordx4/wave
//     (regular VMEM, ~540 inst/CU -- 30x less pipe pressure).
//   - weights = wave-uniform scalars from pre-transposed wT[f][k] in d_ws
//     (s_load_dwordx16-friendly; v_add_f32 v,s,v uses them directly).
//   - wave = 2 output rows x 32 cols (wo>=30 masked) x 4 filters;
//     grid = 15*8*16 = 1920 single-wave blocks -> 7.5 waves/CU.
//   - no LDS, no barriers, full K per wave (exact; absmax 0).
//   - ~55 VGPRs by design (v3/v4 lesson: allocator targets 64, spills if over).

#define C_IN 32
#define NF 64
#define H_OUT 30
#define W_OUT 30
#define W_IN 32
#define KTOT 288   // 9 * 32

static __device__ __forceinline__ float max3f(float a, float b, float c) {
    return fmaxf(fmaxf(a, b), c);
}
static __device__ __forceinline__ float min3f(float a, float b, float c) {
    return fminf(fminf(a, b), c);
}

// wT[f][k] = w[k][f]  (72 KB into d_ws; makes weight rows contiguous in k
// so the main kernel's uniform reads batch as s_load_dwordx16)
__global__ __launch_bounds__(256) void transpose_w_kernel(
    const float* __restrict__ w, float* __restrict__ wT) {
    const int idx = blockIdx.x * 256 + threadIdx.x;   // 0 .. 18431
    if (idx < KTOT * NF) {
        const int f = idx / KTOT;
        const int k = idx - f * KTOT;
        wT[idx] = w[k * NF + f];
    }
}

__global__ __launch_bounds__(64) void tropconv_kernel(
    const float* __restrict__ x,
    const float* __restrict__ wT,
    float* __restrict__ out) {
    const int bx = blockIdx.x;             // 0..1919
    const int fg = bx & 15;                // filter group: f = fg*4 + fi
    const int bb = bx >> 4;                // 0..119
    const int b = bb / 15;
    const int rp = bb - b * 15;            // row pair: rows 2rp, 2rp+1

    const int lane = threadIdx.x;          // 0..63
    const int wo_raw = lane & 31;          // 0..31 (30,31 masked at store)
    const int r = lane >> 5;               // 0 or 1
    const int row = rp * 2 + r;            // output row 0..29
    const int wo = (wo_raw < W_OUT) ? wo_raw : (W_OUT - 1);  // clamp loads

    // uniform weight base for this filter group (contiguous in k)
    const float* __restrict__ wt0 = wT + (size_t)(fg * 4) * KTOT;

    float mx[4], mn[4];
    #pragma unroll
    for (int fi = 0; fi < 4; ++fi) { mx[fi] = -INFINITY; mn[fi] = INFINITY; }

    #pragma unroll
    for (int i = 0; i < 3; ++i) {
        #pragma unroll
        for (int j = 0; j < 3; ++j) {
            const int ij = i * 3 + j;
            // per-lane patch chunk: x[b, row+i, wo+j, 0..31]  (8 x float4)
            const float4* __restrict__ pp = (const float4*)(
                x + ((size_t)((b * 32 + row + i) * W_IN + (wo + j))) * C_IN);
            float4 p[8];
            #pragma unroll
            for (int c4 = 0; c4 < 8; ++c4) p[c4] = pp[c4];

            #pragma unroll
            for (int fi = 0; fi < 4; ++fi) {
                // uniform row segment wT[fg*4+fi][ij*32 .. +31] -> s_loads
                const float* __restrict__ wr = wt0 + (size_t)fi * KTOT + ij * C_IN;
                #pragma unroll
                for (int c4 = 0; c4 < 8; ++c4) {
                    float s0 = p[c4].x + wr[c4 * 4 + 0];
                    float s1 = p[c4].y + wr[c4 * 4 + 1];
                    float s2 = p[c4].z + wr[c4 * 4 + 2];
                    float s3 = p[c4].w + wr[c4 * 4 + 3];
                    mx[fi] = max3f(max3f(s0, s1, s2), s3, mx[fi]);
                    mn[fi] = min3f(min3f(s0, s1, s2), s3, mn[fi]);
                }
            }
        }
    }

    if (wo_raw < W_OUT) {
        float4 res;
        res.x = mx[0] - mn[0];
        res.y = mx[1] - mn[1];
        res.z = mx[2] - mn[2];
        res.w = mx[3] - mn[3];
        float4* __restrict__ op = (float4*)(
            out + ((size_t)((b * H_OUT + row) * W_OUT + wo_raw)) * NF) + fg;
        *op = res;
    }
}

extern "C" void kernel_launch(void* const* d_in, const int* in_sizes, int n_in,
                              void* d_out, int out_size, void* d_ws, size_t ws_size,
                              hipStream_t stream) {
    const float* x = (const float*)d_in[0];   // 8*32*32*32
    const float* w = (const float*)d_in[1];   // 288*64
    float* out = (float*)d_out;               // 8*30*30*64
    float* wT = (float*)d_ws;                 // 288*64 floats (72 KB) scratch

    transpose_w_kernel<<<dim3(72), dim3(256), 0, stream>>>(w, wT);
    tropconv_kernel<<<dim3(15 * 8 * 16), dim3(64), 0, stream>>>(x, wT, out);
}

// Round 8
// 81.003 us; speedup vs baseline: 1.4002x; 1.4002x over previous
//
#include <hip/hip_runtime.h>

// TropConv2D: out[b,ho,wo,f] = max_k(patch_k + w[k,f]) - min_k(patch_k + w[k,f])
// x: (8,32,32,32) f32 NHWC, w: (288,64) f32, out: (8,30,30,64) f32
// k = (i*3 + j)*32 + c   (TF extract_patches ordering)
//
// v8 = v7 (pixel-in-lane, scalar weights) with the spill fixed.
//   v7 failed on hoisting: fully-unrolled i,j let the scheduler pull 1152
//   uniform weight values + all patch lines into regs (VGPR=256 AND 77 MB
//   scratch stores). v8 makes ij a DYNAMIC loop (unroll disabled) so the
//   live set per iteration is: p[8] float4 (one 128-B L1 line per lane),
//   4x32 uniform weights (s_loads from pre-transposed wT), 8 accumulators
//   -> ~120 regs, no spill.
//   - block = 64 (single wave): the shape where the allocator demonstrably
//     grants 256 VGPRs (v3/v4: block>=256 clamps to 64 and spills).
//   - wave = 2 output rows x 32 cols (lane=pixel), 4 filters (fg 0..15).
//     grid = 8b x 15rp x 16fg = 1920 waves -> ~1.9/SIMD; VALU floor
//     1920 x ~2050 inst x 2cyc / 1024 SIMD ~= 3.2 us.
//   - weights wave-uniform: v_add_f32 v,s,v directly (1 SGPR/inst ok);
//     per-lane patch loads reused across all 4 filters (op-minimal layout).
//   - full K in-wave -> exact (absmax 0), no LDS, no barriers.

#define C_IN 32
#define NF 64
#define H_OUT 30
#define W_OUT 30
#define W_IN 32
#define KTOT 288   // 9 * 32

static __device__ __forceinline__ float max3f(float a, float b, float c) {
    return fmaxf(fmaxf(a, b), c);
}
static __device__ __forceinline__ float min3f(float a, float b, float c) {
    return fminf(fminf(a, b), c);
}

// wT[f][k] = w[k][f]  (72 KB into d_ws; contiguous k per filter so the main
// kernel's uniform weight reads batch as wide s_loads)
__global__ __launch_bounds__(256) void transpose_w_kernel(
    const float* __restrict__ w, float* __restrict__ wT) {
    const int idx = blockIdx.x * 256 + threadIdx.x;   // 0 .. 18431
    if (idx < KTOT * NF) {
        const int f = idx / KTOT;
        const int k = idx - f * KTOT;
        wT[idx] = w[k * NF + f];
    }
}

__global__ __launch_bounds__(64) void tropconv_kernel(
    const float* __restrict__ x,
    const float* __restrict__ wT,
    float* __restrict__ out) {
    const int bx = blockIdx.x;             // 0..1919
    const int fg = bx & 15;                // filter group: f = fg*4 + fi
    const int bb = bx >> 4;                // 0..119
    const int b = bb / 15;
    const int rp = bb - b * 15;            // row pair: rows 2rp, 2rp+1

    const int lane = threadIdx.x;          // 0..63
    const int wo_raw = lane & 31;          // 0..31 (30,31 masked at store)
    const int r = lane >> 5;               // 0 or 1
    const int row = rp * 2 + r;            // output row 0..29
    const int wo = (wo_raw < W_OUT) ? wo_raw : (W_OUT - 1);  // clamp loads

    // uniform weight base for this filter group (contiguous in k)
    const float* __restrict__ wt0 = wT + (size_t)(fg * 4) * KTOT;
    // per-lane patch base (row, col applied per ij)
    const float* __restrict__ xb = x + ((size_t)(b * 32 + row) * W_IN + wo) * C_IN;

    float mx[4], mn[4];
    #pragma unroll
    for (int fi = 0; fi < 4; ++fi) { mx[fi] = -INFINITY; mn[fi] = INFINITY; }

    // DYNAMIC ij loop: keeps live set to one window position (anti-hoist).
    #pragma clang loop unroll(disable)
    for (int ij = 0; ij < 9; ++ij) {
        const int i = ij / 3;              // uniform -> scalar ops
        const int j = ij - i * 3;

        // per-lane patch chunk x[b, row+i, wo+j, 0..31]: 8 float4, all in
        // ONE 128-B cache line per lane (C_IN*4 = 128 B)
        const float4* __restrict__ pp =
            (const float4*)(xb + ((size_t)i * W_IN + j) * C_IN);
        float4 p[8];
        #pragma unroll
        for (int c4 = 0; c4 < 8; ++c4) p[c4] = pp[c4];

        const float* __restrict__ wr0 = wt0 + ij * C_IN;
        #pragma unroll
        for (int fi = 0; fi < 4; ++fi) {
            const float* __restrict__ wr = wr0 + (size_t)fi * KTOT;  // uniform
            #pragma unroll
            for (int c4 = 0; c4 < 8; ++c4) {
                float s0 = p[c4].x + wr[c4 * 4 + 0];
                float s1 = p[c4].y + wr[c4 * 4 + 1];
                float s2 = p[c4].z + wr[c4 * 4 + 2];
                float s3 = p[c4].w + wr[c4 * 4 + 3];
                mx[fi] = max3f(max3f(s0, s1, s2), s3, mx[fi]);
                mn[fi] = min3f(min3f(s0, s1, s2), s3, mn[fi]);
            }
        }
    }

    if (wo_raw < W_OUT) {
        float4 res;
        res.x = mx[0] - mn[0];
        res.y = mx[1] - mn[1];
        res.z = mx[2] - mn[2];
        res.w = mx[3] - mn[3];
        float4* __restrict__ op = (float4*)(
            out + ((size_t)((b * H_OUT + row) * W_OUT + wo_raw)) * NF) + fg;
        *op = res;
    }
}

extern "C" void kernel_launch(void* const* d_in, const int* in_sizes, int n_in,
                              void* d_out, int out_size, void* d_ws, size_t ws_size,
                              hipStream_t stream) {
    const float* x = (const float*)d_in[0];   // 8*32*32*32
    const float* w = (const float*)d_in[1];   // 288*64
    float* out = (float*)d_out;               // 8*30*30*64
    float* wT = (float*)d_ws;                 // 288*64 floats (72 KB) scratch

    transpose_w_kernel<<<dim3(72), dim3(256), 0, stream>>>(w, wT);
    tropconv_kernel<<<dim3(15 * 8 * 16), dim3(64), 0, stream>>>(x, wT, out);
}

// Round 9
// 68.352 us; speedup vs baseline: 1.6593x; 1.1851x over previous
//
#include <hip/hip_runtime.h>

// TropConv2D: out[b,ho,wo,f] = max_k(patch_k + w[k,f]) - min_k(patch_k + w[k,f])
// x: (8,32,32,32) f32 NHWC, w: (288,64) f32, out: (8,30,30,64) f32
// k = (i*3 + j)*32 + c   (TF extract_patches ordering)
//
// v9: lane=pixel + FULL-BANDWIDTH LDS patch reads.
//   v5 (lane=filter) is broadcast-bound: LDS broadcast = 16 B/~12cyc, 63/64 of
//   LDS BW wasted -> 11 us/CU floor. v8 (lane=pixel, global strided) paid 64
//   lines/load. v9 stages the tile coalesced into LDS with CONFLICT-FREE
//   padding and reads per-lane:
//   - LDS layout: addr(r_in, col, c) = r_in*1072 + col*33 + c.
//     col stride 33 (odd) -> 32 lanes hit 32 distinct banks; row stride
//     1072 == 16 (mod 32) -> the two 32-lane halves interleave -> 2 lanes/bank
//     (free, m136). ds_read_b32 moves 256 B/5.8cyc (~30x broadcast).
//   - p[32] patch regs reused across 4 filters/wave; weights wave-uniform
//     s_loads from pre-transposed wT (SGPR file, zero VGPR cost).
//   - grid = 8b x 15rp x 4fgq = 480 blocks x 256 thr (4 waves; wave=fg).
//     Live set ~55 VGPR -> safe under the block>=256 64-VGPR clamp (v3/v4).
//   - ij loop dynamic (unroll disabled) = anti-hoist (v7 lesson).
//   - full K per lane -> exact (absmax 0).

#define C_IN 32
#define NF 64
#define H_OUT 30
#define W_OUT 30
#define W_IN 32
#define KTOT 288            // 9 * 32
#define COLS 33             // padded col stride (dwords)
#define ROWS 1072           // padded row stride (dwords), 1072 % 32 == 16

static __device__ __forceinline__ float max3f(float a, float b, float c) {
    return fmaxf(fmaxf(a, b), c);
}
static __device__ __forceinline__ float min3f(float a, float b, float c) {
    return fminf(fminf(a, b), c);
}

// wT[f][k] = w[k][f]  (72 KB into d_ws; contiguous k per filter -> the main
// kernel's uniform weight reads batch as wide s_loads)
__global__ __launch_bounds__(256) void transpose_w_kernel(
    const float* __restrict__ w, float* __restrict__ wT) {
    const int idx = blockIdx.x * 256 + threadIdx.x;   // 0 .. 18431
    if (idx < KTOT * NF) {
        const int f = idx / KTOT;
        const int k = idx - f * KTOT;
        wT[idx] = w[k * NF + f];
    }
}

__global__ __launch_bounds__(256) void tropconv_kernel(
    const float* __restrict__ x,
    const float* __restrict__ wT,
    float* __restrict__ out) {
    const int bx = blockIdx.x;             // 0..479
    const int fgq = bx & 3;                // filter-quad group
    const int bb = bx >> 2;                // 0..119
    const int b = bb / 15;
    const int rp = bb - b * 15;            // row pair: output rows 2rp, 2rp+1

    const int tid = threadIdx.x;
    const int lane = tid & 63;
    const int wave = __builtin_amdgcn_readfirstlane(tid >> 6);  // uniform 0..3

    const int r = lane >> 5;               // 0/1 -> output row rp*2 + r
    const int wo_raw = lane & 31;          // 0..31 (30,31 masked at store)
    const int wo = (wo_raw < W_OUT) ? wo_raw : (W_OUT - 1);
    const int row = rp * 2 + r;

    __shared__ float xs[4 * ROWS];         // 17152 B padded tile

    // ---- Stage 4 input rows (16 KB contiguous) coalesced -> padded LDS ----
    {
        const float4* __restrict__ src4 = (const float4*)(
            x + (size_t)((b * 32 + rp * 2) * W_IN) * C_IN);
        #pragma unroll
        for (int qq = 0; qq < 4; ++qq) {
            const int s4 = tid * 4 + qq;           // float4 index 0..1023
            float4 v = src4[s4];
            const int s = s4 * 4;                  // dword index
            const int rr = s >> 10;
            const int rem = s & 1023;
            const int cc = rem >> 5;
            const int c = rem & 31;
            const int dst = rr * ROWS + cc * COLS + c;
            xs[dst + 0] = v.x;
            xs[dst + 1] = v.y;
            xs[dst + 2] = v.z;
            xs[dst + 3] = v.w;
        }
    }
    __syncthreads();

    // uniform weight base: filters f_base .. f_base+3, contiguous in k
    const int f_base = __builtin_amdgcn_readfirstlane(fgq * 16 + wave * 4);
    const float* __restrict__ wtb = wT + (size_t)f_base * KTOT;

    const int lbase = r * ROWS + wo * COLS;

    float mx[4], mn[4];
    #pragma unroll
    for (int fi = 0; fi < 4; ++fi) { mx[fi] = -INFINITY; mn[fi] = INFINITY; }

    #pragma clang loop unroll(disable)
    for (int ij = 0; ij < 9; ++ij) {
        const int i = ij / 3;              // uniform scalar
        const int j = ij - i * 3;

        // per-lane patch: 32 channels, conflict-free b32 reads
        const float* __restrict__ pb = xs + lbase + i * ROWS + j * COLS;
        float p[32];
        #pragma unroll
        for (int c = 0; c < 32; ++c) p[c] = pb[c];

        const float* __restrict__ wr0 = wtb + ij * C_IN;
        #pragma unroll
        for (int fi = 0; fi < 4; ++fi) {
            const float* __restrict__ wr = wr0 + (size_t)fi * KTOT;  // uniform
            #pragma unroll
            for (int q4 = 0; q4 < 8; ++q4) {
                float s0 = p[q4 * 4 + 0] + wr[q4 * 4 + 0];
                float s1 = p[q4 * 4 + 1] + wr[q4 * 4 + 1];
                float s2 = p[q4 * 4 + 2] + wr[q4 * 4 + 2];
                float s3 = p[q4 * 4 + 3] + wr[q4 * 4 + 3];
                mx[fi] = max3f(max3f(s0, s1, s2), s3, mx[fi]);
                mn[fi] = min3f(min3f(s0, s1, s2), s3, mn[fi]);
            }
        }
    }

    if (wo_raw < W_OUT) {
        float4 res;
        res.x = mx[0] - mn[0];
        res.y = mx[1] - mn[1];
        res.z = mx[2] - mn[2];
        res.w = mx[3] - mn[3];
        float4* __restrict__ op = (float4*)(
            out + ((size_t)((b * H_OUT + row) * W_OUT + wo_raw)) * NF
                + f_base);
        *op = res;
    }
}

extern "C" void kernel_launch(void* const* d_in, const int* in_sizes, int n_in,
                              void* d_out, int out_size, void* d_ws, size_t ws_size,
                              hipStream_t stream) {
    const float* x = (const float*)d_in[0];   // 8*32*32*32
    const float* w = (const float*)d_in[1];   // 288*64
    float* out = (float*)d_out;               // 8*30*30*64
    float* wT = (float*)d_ws;                 // 288*64 floats (72 KB) scratch

    transpose_w_kernel<<<dim3(72), dim3(256), 0, stream>>>(w, wT);
    tropconv_kernel<<<dim3(8 * 15 * 4), dim3(256), 0, stream>>>(x, wT, out);
}